// Round 15
// baseline (360.666 us; speedup 1.0000x reference)
//
#include <hip/hip_runtime.h>
#include <math.h>

#define N_DST 50000
#define N_SRC 50000
#define NEDGE 500000
#define D 128
#define NH 8
#define HD 16
#define BM 64  // rows per block in k_gemm
#define NSB 49 // scan blocks (1024 nodes each)

// ---------------------------------------------------------------------------
// k_prep: block 0: A1T[h][k]=(W1@W4)[k][h] + a3; block 1: A2T from W2.
// ---------------------------------------------------------------------------
__global__ __launch_bounds__(256) void k_prep(const float* __restrict__ W1,
                                              const float* __restrict__ W2,
                                              const float* __restrict__ W3,
                                              const float* __restrict__ W4,
                                              float* __restrict__ A1T,
                                              float* __restrict__ A2T,
                                              float* __restrict__ a3) {
  __shared__ float sW4[D * NH];  // [j][h] as stored
  int tid = threadIdx.x;
  for (int i = tid; i < D * NH / 4; i += 256)
    ((float4*)sW4)[i] = ((const float4*)W4)[i];
  __syncthreads();
  const float* W = blockIdx.x ? W2 : W1;
  float* A = blockIdx.x ? A2T : A1T;
  if (tid < D) {
    int k = tid;
    float acc[NH];
#pragma unroll
    for (int h = 0; h < NH; ++h) acc[h] = 0.f;
    for (int j = 0; j < D; j += 4) {
      float4 w = *(const float4*)(W + (size_t)k * D + j);
#pragma unroll
      for (int h = 0; h < NH; ++h) {
        acc[h] += w.x * sW4[(j + 0) * NH + h] + w.y * sW4[(j + 1) * NH + h] +
                  w.z * sW4[(j + 2) * NH + h] + w.w * sW4[(j + 3) * NH + h];
      }
    }
#pragma unroll
    for (int h = 0; h < NH; ++h) A[h * D + k] = acc[h];
  } else if (blockIdx.x == 0 && tid >= 128 && tid < 128 + NH) {
    int h = tid - 128;
    float s = 0.f;
    for (int k = 0; k < D; ++k) s += W3[k] * sW4[k * NH + h];
    a3[h] = s;
  }
}

// ---------------------------------------------------------------------------
// k_gemm_fused: blocks [0,nblk) GEMM+attn for set A; [nblk,2nblk) set B.
// W read directly from global (L1/L2-resident, one 512B segment/wave/k);
// rows + AT staged in LDS (38.8 KB -> 4 blocks/CU).
// ---------------------------------------------------------------------------
#define FMA4(A, S) \
  A.x += w.x * (S); A.y += w.y * (S); A.z += w.z * (S); A.w += w.w * (S);

__global__ __launch_bounds__(256, 4) void k_gemm_fused(
    const float* __restrict__ featsA, const float* __restrict__ featsB,
    const float* __restrict__ WA, const float* __restrict__ WB,
    const float* __restrict__ ATA, const float* __restrict__ ATB,
    float* __restrict__ outVA, float* __restrict__ outVB,
    float* __restrict__ outAttnA, float* __restrict__ outAttnB, int nrows,
    int nblk) {
  __shared__ float sRT[D][BM + 4];  // 34.8 KB, k-major transposed rows
  __shared__ float sAT[NH * D];     // 4 KB
  int tid = threadIdx.x;
  int bid = blockIdx.x;
  bool first = bid < nblk;
  const float* feats = first ? featsA : featsB;
  const float* W = first ? WA : WB;
  const float* AT = first ? ATA : ATB;
  float* outV = first ? outVA : outVB;
  float* outAttn = first ? outAttnA : outAttnB;
  int rowbase = (first ? bid : bid - nblk) * BM;
  ((float4*)sAT)[tid] = ((const float4*)AT)[tid];  // 1024 floats = AT[8][128]
  {
    int r = tid & 63, k0 = (tid >> 6) * 32;
    int row = rowbase + r;
    if (row >= nrows) row = nrows - 1;
    const float4* f4 = (const float4*)(feats + (size_t)row * D + k0);
#pragma unroll
    for (int j = 0; j < 8; ++j) {
      float4 v = f4[j];
      int k = k0 + j * 4;
      sRT[k + 0][r] = v.x;
      sRT[k + 1][r] = v.y;
      sRT[k + 2][r] = v.z;
      sRT[k + 3][r] = v.w;
    }
  }
  __syncthreads();
  int lane = tid & 63, wid = tid >> 6;
  int rw = wid * 16;
  int half = lane >> 5;
  int cl = lane & 31;
  float4 acc[8];
#pragma unroll
  for (int i = 0; i < 8; ++i) acc[i] = make_float4(0.f, 0.f, 0.f, 0.f);
  const float4* Wg = (const float4*)W;  // W[k][4c] = Wg[k*32 + c]
#pragma unroll 8
  for (int k = 0; k < D; ++k) {
    float4 w = Wg[k * 32 + cl];
    const float* bp = &sRT[k][rw + half * 8];
    float4 ba = *(const float4*)bp;
    float4 bb = *(const float4*)(bp + 4);
    FMA4(acc[0], ba.x); FMA4(acc[1], ba.y); FMA4(acc[2], ba.z); FMA4(acc[3], ba.w);
    FMA4(acc[4], bb.x); FMA4(acc[5], bb.y); FMA4(acc[6], bb.z); FMA4(acc[7], bb.w);
  }
#pragma unroll
  for (int i = 0; i < 8; ++i) {
    int row = rowbase + rw + half * 8 + i;
    if (row < nrows) ((float4*)(outV + (size_t)row * D))[cl] = acc[i];
  }
  // ---- attention projection: outAttn[row][h] = row . AT[h] (AT in LDS) ----
  {
    int r = tid & 63;   // row within block
    int hp = tid >> 6;  // head pair (wave-uniform)
    int h0 = hp * 2, h1 = h0 + 1;
    float p0 = 0.f, p1 = 0.f;
#pragma unroll 8
    for (int k = 0; k < D; ++k) {
      float v = sRT[k][r];
      p0 += v * sAT[h0 * D + k];  // wave-uniform -> LDS broadcast
      p1 += v * sAT[h1 * D + k];
    }
    int row = rowbase + r;
    if (row < nrows) {
      outAttn[(size_t)row * NH + h0] = p0;
      outAttn[(size_t)row * NH + h1] = p1;
    }
  }
}

// ---------------------------------------------------------------------------
// k_out_fused: out = LN(agg @ Wout + Wout_b + R + res_b) * g + b
// Wout read from global (L2-hot); rows staged in LDS.
// ---------------------------------------------------------------------------
__global__ __launch_bounds__(256, 4) void k_out_fused(
    const float* __restrict__ agg, const float* __restrict__ Wout,
    const float* __restrict__ R, const float* __restrict__ Wout_b,
    const float* __restrict__ res_b, const float* __restrict__ ln_g,
    const float* __restrict__ ln_b, float* __restrict__ out, int nrows) {
  __shared__ float sRT[D][BM + 4];
  int tid = threadIdx.x;
  int rowbase = blockIdx.x * BM;
  {
    int r = tid & 63, k0 = (tid >> 6) * 32;
    int row = rowbase + r;
    if (row >= nrows) row = nrows - 1;
    const float4* f4 = (const float4*)(agg + (size_t)row * D + k0);
#pragma unroll
    for (int j = 0; j < 8; ++j) {
      float4 v = f4[j];
      int k = k0 + j * 4;
      sRT[k + 0][r] = v.x;
      sRT[k + 1][r] = v.y;
      sRT[k + 2][r] = v.z;
      sRT[k + 3][r] = v.w;
    }
  }
  __syncthreads();
  int lane = tid & 63, wid = tid >> 6;
  int rw = wid * 16;
  int half = lane >> 5;
  int cl = lane & 31;
  float4 acc[8];
#pragma unroll
  for (int i = 0; i < 8; ++i) acc[i] = make_float4(0.f, 0.f, 0.f, 0.f);
  const float4* Wg = (const float4*)Wout;
#pragma unroll 8
  for (int k = 0; k < D; ++k) {
    float4 w = Wg[k * 32 + cl];
    const float* bp = &sRT[k][rw + half * 8];
    float4 ba = *(const float4*)bp;
    float4 bb = *(const float4*)(bp + 4);
    FMA4(acc[0], ba.x); FMA4(acc[1], ba.y); FMA4(acc[2], ba.z); FMA4(acc[3], ba.w);
    FMA4(acc[4], bb.x); FMA4(acc[5], bb.y); FMA4(acc[6], bb.z); FMA4(acc[7], bb.w);
  }
  float4 wb = ((const float4*)Wout_b)[cl];
  float4 rb = ((const float4*)res_b)[cl];
  float4 g4 = ((const float4*)ln_g)[cl];
  float4 b4 = ((const float4*)ln_b)[cl];
#pragma unroll
  for (int i = 0; i < 8; ++i) {
    int row = rowbase + rw + half * 8 + i;
    int rc = (row < nrows) ? row : (nrows - 1);
    float4 rr = ((const float4*)(R + (size_t)rc * D))[cl];
    float4 y;
    y.x = acc[i].x + wb.x + rb.x + rr.x;
    y.y = acc[i].y + wb.y + rb.y + rr.y;
    y.z = acc[i].z + wb.z + rb.z + rr.z;
    y.w = acc[i].w + wb.w + rb.w + rr.w;
    float s = y.x + y.y + y.z + y.w;
#pragma unroll
    for (int off = 1; off < 32; off <<= 1) s += __shfl_xor(s, off);
    float mu = s * (1.f / D);
    float4 dx;
    dx.x = y.x - mu; dx.y = y.y - mu; dx.z = y.z - mu; dx.w = y.w - mu;
    float sq = dx.x * dx.x + dx.y * dx.y + dx.z * dx.z + dx.w * dx.w;
#pragma unroll
    for (int off = 1; off < 32; off <<= 1) sq += __shfl_xor(sq, off);
    float rstd = rsqrtf(sq * (1.f / D) + 1e-5f);
    float4 o;
    o.x = dx.x * rstd * g4.x + b4.x;
    o.y = dx.y * rstd * g4.y + b4.y;
    o.z = dx.z * rstd * g4.z + b4.z;
    o.w = dx.w * rstd * g4.w + b4.w;
    if (row < nrows) ((float4*)(out + (size_t)row * D))[cl] = o;
  }
}

// ---------------------------------------------------------------------------
// k_hist: histogram of dst indices (separate launch, proven pattern)
// ---------------------------------------------------------------------------
__global__ void k_hist(const int* __restrict__ dsti, int* __restrict__ deg) {
  int e = blockIdx.x * 256 + threadIdx.x;
  if (e < NEDGE) atomicAdd(&deg[dsti[e]], 1);
}

// ---------------------------------------------------------------------------
// k_scan_all: single-kernel exclusive scan of deg -> offs,pos.
// Each of the 49 blocks redundantly sums deg[0 .. b*1024) (L2-hot), then
// scans its own 1024-chunk. Last block writes offs[N_DST].
// ---------------------------------------------------------------------------
__global__ __launch_bounds__(256) void k_scan_all(const int* __restrict__ deg,
                                                  int* __restrict__ offs,
                                                  int* __restrict__ pos) {
  __shared__ int ws1[4];
  __shared__ int ws2[4];
  __shared__ int sPre;
  int tid = threadIdx.x, lane = tid & 63, wid = tid >> 6;
  int b = blockIdx.x;
  int pre = 0;
  int lim = b * 1024;
  for (int i = tid * 4; i < lim; i += 1024) {
    int4 v = *(const int4*)(deg + i);
    pre += v.x + v.y + v.z + v.w;
  }
#pragma unroll
  for (int o = 1; o < 64; o <<= 1) pre += __shfl_xor(pre, o);
  if (lane == 0) ws1[wid] = pre;
  __syncthreads();
  if (tid == 0) sPre = ws1[0] + ws1[1] + ws1[2] + ws1[3];
  int base = b * 1024 + tid * 4;
  int v0 = (base + 0 < N_DST) ? deg[base + 0] : 0;
  int v1 = (base + 1 < N_DST) ? deg[base + 1] : 0;
  int v2 = (base + 2 < N_DST) ? deg[base + 2] : 0;
  int v3 = (base + 3 < N_DST) ? deg[base + 3] : 0;
  int ts = v0 + v1 + v2 + v3;
  int s = ts;
#pragma unroll
  for (int o = 1; o < 64; o <<= 1) {
    int t = __shfl_up(s, o);
    if (lane >= o) s += t;
  }
  if (lane == 63) ws2[wid] = s;
  __syncthreads();
  int woff = 0;
  for (int i = 0; i < wid; ++i) woff += ws2[i];
  int tb = sPre + woff + (s - ts);
  if (base + 0 < N_DST) { offs[base + 0] = tb; pos[base + 0] = tb; }
  tb += v0;
  if (base + 1 < N_DST) { offs[base + 1] = tb; pos[base + 1] = tb; }
  tb += v1;
  if (base + 2 < N_DST) { offs[base + 2] = tb; pos[base + 2] = tb; }
  tb += v2;
  if (base + 3 < N_DST) { offs[base + 3] = tb; pos[base + 3] = tb; }
  if (b == NSB - 1 && tid == 0)
    offs[N_DST] = sPre + ws2[0] + ws2[1] + ws2[2] + ws2[3];
}

// scatter: one packed 16B record per edge: (src_bits, P, det, 0)
__global__ void k_scatter(const int* __restrict__ srci, const int* __restrict__ dsti,
                          const float* __restrict__ P, const float* __restrict__ det,
                          int* __restrict__ pos, float4* __restrict__ csr_pk) {
  int e = blockIdx.x * 256 + threadIdx.x;
  if (e >= NEDGE) return;
  int d = dsti[e];
  int sidx = srci[e];
  float pe = P[e], de = det[e];
  int p = atomicAdd(&pos[d], 1);
  csr_pk[p] = make_float4(__int_as_float(sidx), pe, de, 0.f);
}

// ---------------------------------------------------------------------------
// k_main: 8 lanes per dst node, one lane per head. Single pass, direct exp
// (logits ~N(0,4), |x| <= ~11 << 88 overflow bound -> exp(x) safe; softmax
// quotient identical to max-shifted form).
// ---------------------------------------------------------------------------
__global__ __launch_bounds__(256) void k_main(
    const int* __restrict__ offs, const float4* __restrict__ csr_pk,
    const float* __restrict__ attn_src, const float* __restrict__ attn_dst,
    const float* __restrict__ a3g, const float* __restrict__ V,
    float* __restrict__ agg) {
  int tid = threadIdx.x;
  int g = tid >> 3;   // node group within block (0..31)
  int h = tid & 7;    // head
  int node = blockIdx.x * 32 + g;
  if (node >= N_DST) return;
  int start = offs[node], end = offs[node + 1];
  float ad = attn_dst[(size_t)node * NH + h];
  float a3h = a3g[h];

  float4 a0 = make_float4(0.f, 0.f, 0.f, 0.f);
  float4 a1 = a0, a2 = a0, a3v = a0;
  float ssum = 0.f;
#pragma unroll 2
  for (int e = start; e < end; ++e) {
    float4 pk = csr_pk[e];  // broadcast within 8-lane group
    int sidx = __float_as_int(pk.x);
    float x = ad + attn_src[(size_t)sidx * NH + h] + pk.y * a3h + pk.z;
    x = (x > 0.f) ? x : 0.2f * x;  // leaky_relu(0.2)
    float w = __expf(x);
    ssum += w;
    const float4* v4 = (const float4*)(V + (size_t)sidx * D + h * HD);
    float4 b0 = v4[0], b1 = v4[1], b2 = v4[2], b3 = v4[3];
    a0.x += w * b0.x; a0.y += w * b0.y; a0.z += w * b0.z; a0.w += w * b0.w;
    a1.x += w * b1.x; a1.y += w * b1.y; a1.z += w * b1.z; a1.w += w * b1.w;
    a2.x += w * b2.x; a2.y += w * b2.y; a2.z += w * b2.z; a2.w += w * b2.w;
    a3v.x += w * b3.x; a3v.y += w * b3.y; a3v.z += w * b3.z; a3v.w += w * b3.w;
  }
  float inv = 1.f / (ssum + 1e-12f);
  float4* o = (float4*)(agg + (size_t)node * D + h * HD);
  a0.x *= inv; a0.y *= inv; a0.z *= inv; a0.w *= inv;
  a1.x *= inv; a1.y *= inv; a1.z *= inv; a1.w *= inv;
  a2.x *= inv; a2.y *= inv; a2.z *= inv; a2.w *= inv;
  a3v.x *= inv; a3v.y *= inv; a3v.z *= inv; a3v.w *= inv;
  o[0] = a0; o[1] = a1; o[2] = a2; o[3] = a3v;
}

// ---------------------------------------------------------------------------
extern "C" void kernel_launch(void* const* d_in, const int* in_sizes, int n_in,
                              void* d_out, int out_size, void* d_ws, size_t ws_size,
                              hipStream_t stream) {
  const float* dst_feats = (const float*)d_in[0];
  const float* src_feats = (const float*)d_in[1];
  const int* edge_index = (const int*)d_in[2];
  const float* P_edge = (const float*)d_in[3];
  const float* deter = (const float*)d_in[4];
  const float* W1 = (const float*)d_in[5];
  const float* W2 = (const float*)d_in[6];
  const float* W3 = (const float*)d_in[7];
  const float* W4 = (const float*)d_in[8];
  const float* Wv = (const float*)d_in[9];
  const float* Wout_w = (const float*)d_in[10];
  const float* Wout_b = (const float*)d_in[11];
  const float* res_w = (const float*)d_in[12];
  const float* res_b = (const float*)d_in[13];
  const float* ln_g = (const float*)d_in[14];
  const float* ln_b = (const float*)d_in[15];
  float* out = (float*)d_out;
  const int* src_idx = edge_index;
  const int* dst_idx = edge_index + NEDGE;

  float* base = (float*)d_ws;
  size_t off = 0;
  auto alloc = [&](size_t n) {
    float* p = base + off;
    off += (n + 63) & ~(size_t)63;
    return p;
  };
  float* A1T = alloc(1024);
  float* A2T = alloc(1024);
  float* a3 = alloc(8);
  float* attn_dst = alloc((size_t)N_DST * NH);
  float* attn_src = alloc((size_t)N_SRC * NH);
  float* V = alloc((size_t)N_SRC * D);
  float* R = alloc((size_t)N_DST * D);
  float* agg = alloc((size_t)N_DST * D);
  int* deg = (int*)alloc(N_DST);
  int* offs = (int*)alloc(N_DST + 1);
  int* pos = (int*)alloc(N_DST);
  float4* csr_pk = (float4*)alloc((size_t)NEDGE * 4);
  (void)ws_size; (void)in_sizes; (void)n_in; (void)out_size;

  const int NBLK = (N_DST + BM - 1) / BM;  // 782 gemm blocks per half
  const int NHB = (NEDGE + 255) / 256;     // 1954 edge blocks

  hipMemsetAsync(deg, 0, N_DST * sizeof(int), stream);
  k_prep<<<2, 256, 0, stream>>>(W1, W2, W3, W4, A1T, A2T, a3);
  k_gemm_fused<<<2 * NBLK, 256, 0, stream>>>(
      src_feats, dst_feats, Wv, res_w, A2T, A1T, V, R, attn_src, attn_dst,
      N_DST, NBLK);
  k_hist<<<NHB, 256, 0, stream>>>(dst_idx, deg);
  k_scan_all<<<NSB, 256, 0, stream>>>(deg, offs, pos);
  k_scatter<<<NHB, 256, 0, stream>>>(src_idx, dst_idx, P_edge, deter, pos, csr_pk);
  k_main<<<(N_DST + 31) / 32, 256, 0, stream>>>(offs, csr_pk, attn_src, attn_dst,
                                                a3, V, agg);
  k_out_fused<<<NBLK, 256, 0, stream>>>(agg, Wout_w, R, Wout_b, res_b, ln_g, ln_b,
                                        out, N_DST);
}